// Round 1
// 1497.163 us; speedup vs baseline: 1.0822x; 1.0822x over previous
//
#include <hip/hip_runtime.h>

typedef float v2f __attribute__((ext_vector_type(2)));

#define NTOK 8192      // B*S
#define DD 16
#define VV 8192
#define VC 512         // codes per LDS chunk (halved: 2 blocks/CU)
#define NCHUNK 16
#define KS 1.8033688011112042f  // log2(e)/0.8

// d_ws layout (float offsets)
#define WS_CBT 0        // cbT[16][8192]
#define WS_B1  131072   // b*KS
#define WS_T1  139264   // t_proj*KS
#define WS_CC2 147456   // ||c||^2

__global__ __launch_bounds__(256) void prep_kernel(
    const float* __restrict__ cb, const float* __restrict__ bm,
    const float* __restrict__ tp, float* __restrict__ ws) {
  __shared__ float tile[256 * 17];
  float* cbT = ws + WS_CBT;
  float* B1  = ws + WS_B1;
  float* T1  = ws + WS_T1;
  float* CC2 = ws + WS_CC2;
  const int tid = threadIdx.x;
  const int v0 = blockIdx.x * 256;
#pragma unroll
  for (int k = 0; k < 4; k++) {
    int j = tid + (k << 8);
    int v = j >> 2, d4 = (j & 3) << 2;
    float4 f = *(const float4*)(cb + (size_t)(v0 + v) * DD + d4);
    tile[v * 17 + d4 + 0] = f.x;
    tile[v * 17 + d4 + 1] = f.y;
    tile[v * 17 + d4 + 2] = f.z;
    tile[v * 17 + d4 + 3] = f.w;
  }
  __syncthreads();
#pragma unroll
  for (int k = 0; k < 16; k++) {
    int j = tid + (k << 8);
    int d = j >> 8, c = j & 255;
    cbT[(size_t)d * VV + v0 + c] = tile[c * 17 + d];
  }
  int v = v0 + tid;
  float s = 0.f;
#pragma unroll
  for (int d4 = 0; d4 < DD; d4 += 4) {
    float4 f = *(const float4*)(cb + (size_t)v * DD + d4);
    s += f.x * f.x + f.y * f.y + f.z * f.z + f.w * f.w;
  }
  CC2[v] = s;
  B1[v] = bm[v] * KS;
  T1[v] = tp[v] * KS;
}

// R6 redesign for occupancy + spill elimination:
//   - 2 tokens/lane (one v2f) instead of 4: ex2+acc2 = 64 VGPRs (was 128),
//     fits the 128-reg budget -> no scratch (was 274 MB WRITE_SIZE of spills).
//   - VC=512: LDS ~73 KB/block -> 2 blocks/CU, 4 waves/SIMD (Occupancy 23->46%),
//     so one block's stage/barrier drain hides under the other's FMA phase.
//   - Grid 512 blocks x 512 thr = exactly 2 blocks/CU co-resident, no tail.
// Wave-pair structure kept: waves 2k,2k+1 own the same 4 tokens; parity o
// sweeps half the codes of each chunk; partials merged via small LDS exchange.
// CRITICAL (R3/R4 lesson): every private-array-indexing loop fully unrolled.
__global__ __launch_bounds__(512, 4) void flow_kernel(
    const float* __restrict__ x0, const float* __restrict__ Wm,
    const float* __restrict__ ws, const int* __restrict__ nsp,
    float* __restrict__ out) {
  __shared__ float wL[DD * VC];       // 32 KB  W chunk, d-major
  __shared__ float cL[DD * VC];       // 32 KB  cbT chunk, d-major
  __shared__ float b1L[VC];           // 2 KB
  __shared__ float t1L[VC];           // 2 KB
  __shared__ float sL[16 * DD];       // 1 KB saved state across midpoint halves
  __shared__ float4 redP[8][2][9];    // 2.25 KB cross-wave partial exchange
  __shared__ float redMv[8][2][2];    // VQ argmin exchange
  __shared__ int   redMi[8][2][2];

  const float* cbT = ws + WS_CBT;
  const float* B1  = ws + WS_B1;
  const float* T1  = ws + WS_T1;
  const float* CC2 = ws + WS_CC2;

  const int tid = threadIdx.x;
  const int lane = tid & 63;
  const int wave = tid >> 6;           // 0..7
  const int o = wave & 1;              // parity: which half of the code range
  const int wp = wave >> 1;            // pair id 0..3
  const int half = lane >> 5;          // 0 or 1
  const int hl = lane & 31;            // lane within half
  const int tokBase = blockIdx.x * 16 + wp * 4 + half * 2;
  const int sbase = wp * 4 + half * 2;

  const int n_steps = *nsp;
  const float dt = 1.0f / (float)(n_steps - 1);

  // v2f: .x = token tokBase, .y = token tokBase+1
  v2f ex2[DD];
#pragma unroll
  for (int d = 0; d < DD; d++) {
    ex2[d].x = x0[(size_t)tokBase * DD + d];
    ex2[d].y = x0[(size_t)(tokBase + 1) * DD + d];
  }
  if (o == 0 && hl == 0) {
#pragma unroll
    for (int d = 0; d < DD; d++) {
      sL[sbase * DD + d]       = ex2[d].x;
      sL[(sbase + 1) * DD + d] = ex2[d].y;
    }
  }

  for (int step = 0; step < n_steps - 1; step++) {
    const float tbase = (float)step * dt;
#pragma unroll 1
    for (int mh = 0; mh < 2; mh++) {
      const float tt = tbase + (mh ? 0.5f * dt : 0.0f);
      v2f acc2[DD];
      v2f l2 = (v2f){0.f, 0.f};
#pragma unroll
      for (int d = 0; d < DD; d++) acc2[d] = (v2f){0.f, 0.f};
#pragma unroll 1
      for (int c = 0; c < NCHUNK; c++) {
        __syncthreads();
        const int v0 = c * VC;
#pragma unroll
        for (int k = 0; k < 4; k++) {
          int j = tid + (k << 9);
          int row = j >> 7;
          int col = (j & 127) << 2;
          *(float4*)(wL + row * VC + col) =
              *(const float4*)(Wm + (size_t)row * VV + v0 + col);
        }
#pragma unroll
        for (int k = 0; k < 4; k++) {
          int j = tid + (k << 9);
          int row = j >> 7;
          int col = (j & 127) << 2;
          *(float4*)(cL + row * VC + col) =
              *(const float4*)(cbT + (size_t)row * VV + v0 + col);
        }
        if (tid < 128) {
          int col = tid << 2;
          *(float4*)(b1L + col) = *(const float4*)(B1 + v0 + col);
        } else if (tid < 256) {
          int col = (tid - 128) << 2;
          *(float4*)(t1L + col) = *(const float4*)(T1 + v0 + col);
        }
        __syncthreads();
#pragma unroll 1
        for (int p = 0; p < 2; p++) {
          const int vb = (o << 8) + (p << 7) + (hl << 2);  // this wave's 4 codes
          v2f e2[4];
#pragma unroll
          for (int j = 0; j < 4; j++) e2[j] = (v2f){0.f, 0.f};
#pragma unroll
          for (int d = 0; d < DD; d++) {
            float4 w4 = *(const float4*)(wL + d * VC + vb);
            v2f w0 = {w4.x, w4.x}, w1 = {w4.y, w4.y};
            v2f w2 = {w4.z, w4.z}, w3 = {w4.w, w4.w};
            e2[0] = __builtin_elementwise_fma(ex2[d], w0, e2[0]);
            e2[1] = __builtin_elementwise_fma(ex2[d], w1, e2[1]);
            e2[2] = __builtin_elementwise_fma(ex2[d], w2, e2[2]);
            e2[3] = __builtin_elementwise_fma(ex2[d], w3, e2[3]);
          }
          float4 bb = *(const float4*)(b1L + vb);
          float4 tb = *(const float4*)(t1L + vb);
          v2f bias0 = {fmaf(tt, tb.x, bb.x), fmaf(tt, tb.x, bb.x)};
          v2f bias1 = {fmaf(tt, tb.y, bb.y), fmaf(tt, tb.y, bb.y)};
          v2f bias2 = {fmaf(tt, tb.z, bb.z), fmaf(tt, tb.z, bb.z)};
          v2f bias3 = {fmaf(tt, tb.w, bb.w), fmaf(tt, tb.w, bb.w)};
          const v2f ks2 = {KS, KS};
          e2[0] = __builtin_elementwise_fma(e2[0], ks2, bias0);
          e2[1] = __builtin_elementwise_fma(e2[1], ks2, bias1);
          e2[2] = __builtin_elementwise_fma(e2[2], ks2, bias2);
          e2[3] = __builtin_elementwise_fma(e2[3], ks2, bias3);
#pragma unroll
          for (int j = 0; j < 4; j++) {
            e2[j].x = exp2f(e2[j].x);
            e2[j].y = exp2f(e2[j].y);
          }
          l2 += (e2[0] + e2[1]) + (e2[2] + e2[3]);
#pragma unroll
          for (int d = 0; d < DD; d++) {
            float4 c4 = *(const float4*)(cL + d * VC + vb);
            v2f c0 = {c4.x, c4.x}, c1 = {c4.y, c4.y};
            v2f c2 = {c4.z, c4.z}, c3 = {c4.w, c4.w};
            v2f a = acc2[d];
            a = __builtin_elementwise_fma(e2[0], c0, a);
            a = __builtin_elementwise_fma(e2[1], c1, a);
            a = __builtin_elementwise_fma(e2[2], c2, a);
            a = __builtin_elementwise_fma(e2[3], c3, a);
            acc2[d] = a;
          }
        }
      }
      // in-wave butterfly over the 32 lanes of each half — FULLY UNROLLED
#pragma unroll
      for (int m = 1; m < 32; m <<= 1) {
        l2.x += __shfl_xor(l2.x, m, 64);
        l2.y += __shfl_xor(l2.y, m, 64);
      }
#pragma unroll
      for (int d = 0; d < DD; d++) {
#pragma unroll
        for (int m = 1; m < 32; m <<= 1) {
          acc2[d].x += __shfl_xor(acc2[d].x, m, 64);
          acc2[d].y += __shfl_xor(acc2[d].y, m, 64);
        }
      }
      // cross-wave (pair) combine via LDS
      if (hl == 0) {
#pragma unroll
        for (int d = 0; d < DD; d += 2) {
          redP[wave][half][d >> 1] =
              make_float4(acc2[d].x, acc2[d].y, acc2[d + 1].x, acc2[d + 1].y);
        }
        redP[wave][half][8] = make_float4(l2.x, l2.y, 0.f, 0.f);
      }
      __syncthreads();
      {
        const int pw = wave ^ 1;
#pragma unroll
        for (int d = 0; d < DD; d += 2) {
          float4 f0 = redP[pw][half][d >> 1];
          acc2[d].x += f0.x; acc2[d].y += f0.y;
          acc2[d + 1].x += f0.z; acc2[d + 1].y += f0.w;
        }
        float4 fl = redP[pw][half][8];
        l2.x += fl.x; l2.y += fl.y;
      }
      // epilogue: ex update — FULLY UNROLLED (both waves compute identically)
      const float inv1 = 1.0f / (1.0f - tt + 1e-10f);
      const float cf = (mh == 0) ? (0.5f * dt * inv1) : (dt * inv1);
      const float ilx = 1.0f / l2.x, ily = 1.0f / l2.y;
#pragma unroll
      for (int d = 0; d < DD; d++) {
        const float mux = acc2[d].x * ilx, muy = acc2[d].y * ily;
        if (mh == 0) {
          ex2[d].x = fmaf(cf, mux - ex2[d].x, ex2[d].x);
          ex2[d].y = fmaf(cf, muy - ex2[d].y, ex2[d].y);
        } else {
          const float svx = sL[sbase * DD + d];
          const float svy = sL[(sbase + 1) * DD + d];
          ex2[d].x = fmaf(cf, mux - ex2[d].x, svx);
          ex2[d].y = fmaf(cf, muy - ex2[d].y, svy);
        }
      }
      if (mh == 1) {
        __syncthreads();
        if (o == 0 && hl == 0) {
#pragma unroll
          for (int d = 0; d < DD; d++) {
            sL[sbase * DD + d]       = ex2[d].x;
            sL[(sbase + 1) * DD + d] = ex2[d].y;
          }
        }
      }
    }
  }

  // ---- VQ argmin: d = ||c||^2 - 2 x.c ; wave o sweeps codes [o*4096, +4096) ----
  v2f minv = (v2f){3.402823466e38f, 3.402823466e38f};
  int mix = 0, miy = 0;
#pragma unroll 1
  for (int p = 0; p < 32; p++) {
    const int v4 = (o << 12) + (p << 7) + (hl << 2);
    v2f dot2[4];
#pragma unroll
    for (int j = 0; j < 4; j++) dot2[j] = (v2f){0.f, 0.f};
#pragma unroll
    for (int d = 0; d < DD; d++) {
      float4 c4 = *(const float4*)(cbT + (size_t)d * VV + v4);   // L2-resident
      v2f c0 = {c4.x, c4.x}, c1 = {c4.y, c4.y};
      v2f c2 = {c4.z, c4.z}, c3 = {c4.w, c4.w};
      dot2[0] = __builtin_elementwise_fma(ex2[d], c0, dot2[0]);
      dot2[1] = __builtin_elementwise_fma(ex2[d], c1, dot2[1]);
      dot2[2] = __builtin_elementwise_fma(ex2[d], c2, dot2[2]);
      dot2[3] = __builtin_elementwise_fma(ex2[d], c3, dot2[3]);
    }
    float4 cc = *(const float4*)(CC2 + v4);
#pragma unroll
    for (int j = 0; j < 4; j++) {
      const float ccj = (j == 0) ? cc.x : (j == 1) ? cc.y : (j == 2) ? cc.z : cc.w;
      float dx = fmaf(-2.f, dot2[j].x, ccj);
      float dy = fmaf(-2.f, dot2[j].y, ccj);
      if (dx < minv.x) { minv.x = dx; mix = v4 + j; }
      if (dy < minv.y) { minv.y = dy; miy = v4 + j; }
    }
  }
  // in-wave argmin butterfly (within half)
#pragma unroll
  for (int m = 1; m < 32; m <<= 1) {
    float ovx = __shfl_xor(minv.x, m, 64);
    int oix = __shfl_xor(mix, m, 64);
    if (ovx < minv.x || (ovx == minv.x && oix < mix)) { minv.x = ovx; mix = oix; }
    float ovy = __shfl_xor(minv.y, m, 64);
    int oiy = __shfl_xor(miy, m, 64);
    if (ovy < minv.y || (ovy == minv.y && oiy < miy)) { minv.y = ovy; miy = oiy; }
  }
  // cross-wave argmin combine (tie -> smaller index; both waves converge)
  if (hl == 0) {
    redMv[wave][half][0] = minv.x; redMi[wave][half][0] = mix;
    redMv[wave][half][1] = minv.y; redMi[wave][half][1] = miy;
  }
  __syncthreads();
  {
    const int pw = wave ^ 1;
    float ov; int oi;
    ov = redMv[pw][half][0]; oi = redMi[pw][half][0];
    if (ov < minv.x || (ov == minv.x && oi < mix)) { minv.x = ov; mix = oi; }
    ov = redMv[pw][half][1]; oi = redMi[pw][half][1];
    if (ov < minv.y || (ov == minv.y && oi < miy)) { minv.y = ov; miy = oi; }
  }

  // ---- outputs (fp32): x_final (131072) then indices-as-float (8192) ----
  if (o == 0) {
    if (hl == 0) {
      const int tok = tokBase;
#pragma unroll
      for (int d = 0; d < DD; d++) out[(size_t)tok * DD + d] = ex2[d].x;
      out[(size_t)NTOK * DD + tok] = (float)mix;
    } else if (hl == 1) {
      const int tok = tokBase + 1;
#pragma unroll
      for (int d = 0; d < DD; d++) out[(size_t)tok * DD + d] = ex2[d].y;
      out[(size_t)NTOK * DD + tok] = (float)miy;
    }
  }
}

extern "C" void kernel_launch(void* const* d_in, const int* in_sizes, int n_in,
                              void* d_out, int out_size, void* d_ws, size_t ws_size,
                              hipStream_t stream) {
  const float* x0 = (const float*)d_in[0];
  const float* cb = (const float*)d_in[1];
  const float* Wm = (const float*)d_in[2];
  const float* bm = (const float*)d_in[3];
  const float* tp = (const float*)d_in[4];
  const int* ns   = (const int*)d_in[5];
  float* ws = (float*)d_ws;               // needs 622592 B
  float* out = (float*)d_out;             // fp32 outputs, concatenated flat

  prep_kernel<<<32, 256, 0, stream>>>(cb, bm, tp, ws);
  flow_kernel<<<512, 512, 0, stream>>>(x0, Wm, ws, ns, out);
}

// Round 3
// 833.366 us; speedup vs baseline: 1.9441x; 1.7965x over previous
//
#include <hip/hip_runtime.h>

#define KS 1.8033688011112042f  // log2(e)/0.8
#define NTOK 8192
#define VV 8192
#define CHB 51200
#define WS_CC2B 1638400

typedef float f4 __attribute__((ext_vector_type(4)));
typedef short s8v __attribute__((ext_vector_type(8)));
typedef unsigned int u32;

// RNE float->bf16 helpers, pure bit ops (no inline asm; m240: compiler-friendly)
static __device__ __forceinline__ unsigned short f2bf(float f) {
  u32 u = __float_as_uint(f);
  return (unsigned short)((u + 0x7fffu + ((u >> 16) & 1u)) >> 16);
}
static __device__ __forceinline__ float bfhi(float f) {  // RNE bf16 of f, as f32
  u32 u = __float_as_uint(f);
  u = u + 0x7fffu + ((u >> 16) & 1u);
  return __uint_as_float(u & 0xffff0000u);
}
static __device__ __forceinline__ u32 pkbf(float a, float b) {  // {lo:bf(a),hi:bf(b)}
  u32 ua = __float_as_uint(a), ub = __float_as_uint(b);
  ua = ua + 0x7fffu + ((ua >> 16) & 1u);
  ub = ub + 0x7fffu + ((ub >> 16) & 1u);
  return (ua >> 16) | (ub & 0xffff0000u);
}

// ws layout: 32 chunks (256 codes), chunk-major, one linear 51200-B copy each:
//   [0     ,16384) FragWh : 16 subtiles x 64 lanes x 8 bf16 (A of mfma1, W_hi*KS)
//   [16384 ,32768) FragWl
//   [32768 ,40960) FragCh : 8 PAIRS x 64 lanes x 8 bf16 (A of mfma2, K=32 pairing)
//   [40960 ,49152) FragCl
//   [49152 ,50176) BB fp32[256] (b*KS)   [50176,51200) BT fp32[256] (tp*KS)
// then CC2 fp32[8192]. Total 1671168 B.
//
// ALL mfma are 16x16x32_bf16 (the one instruction whose A/B layout is
// implicitly validated by the refcheck'd GEMM ladder: row=l&15, k=(l>>4)*8+j,
// 8 contiguous k per lane; C/D verified m89: col=l&15, row=(l>>4)*4+reg).
//
// mfma1 (logits^T): M=code16, N=tok16, K=32 ([xh;xl]); A repeats W over d=k&15.
// mfma2 (mu^T):     M=d16,    N=tok16, K=32 over a PAIR of subtiles (p0=2s,
//   p1=2s+1): k=g*8+j maps to code = (j<4 ? p0 : p1)*16 + g*4 + (j&3).
//   A lane l: row=d=l&15, elem j = C[code(k)][d]. B elem j = E[code(k)][tok]
//   -- which is exactly the e-values the lane holds from mfma1's D of p0/p1.
__global__ __launch_bounds__(64) void prep_kernel(
    const float* __restrict__ cb, const float* __restrict__ Wm,
    const float* __restrict__ bm, const float* __restrict__ tp,
    char* __restrict__ ws) {
  const int ct = blockIdx.x;  // subtile 0..511 (16 codes)
  const int l = threadIdx.x;
  const int g = l >> 4, q = l & 15;
  const int c = ct >> 4, p = ct & 15;
  const int s = p >> 1, par = p & 1;
  char* chunk = ws + (size_t)c * CHB;
  {  // W fragment (A of mfma1): row=code=ct*16+q, k=g*8+j, d=k&15
    const int code = ct * 16 + q;
    unsigned short wh[8], wl[8];
#pragma unroll
    for (int j = 0; j < 8; j++) {
      int d = (g * 8 + j) & 15;
      float v = Wm[d * VV + code] * KS;
      unsigned short h = f2bf(v);
      wh[j] = h;
      wl[j] = f2bf(v - __uint_as_float((u32)h << 16));
    }
    uint4 hv, lv;
    hv.x = (u32)wh[0] | ((u32)wh[1] << 16); hv.y = (u32)wh[2] | ((u32)wh[3] << 16);
    hv.z = (u32)wh[4] | ((u32)wh[5] << 16); hv.w = (u32)wh[6] | ((u32)wh[7] << 16);
    lv.x = (u32)wl[0] | ((u32)wl[1] << 16); lv.y = (u32)wl[2] | ((u32)wl[3] << 16);
    lv.z = (u32)wl[4] | ((u32)wl[5] << 16); lv.w = (u32)wl[6] | ((u32)wl[7] << 16);
    *(uint4*)(chunk + p * 1024 + l * 16) = hv;
    *(uint4*)(chunk + 16384 + p * 1024 + l * 16) = lv;
  }
  {  // C pair-fragment (A of mfma2): this block fills elems par*4+{0..3} of pair s
    unsigned short ch[4], cl_[4];
#pragma unroll
    for (int j = 0; j < 4; j++) {
      int code = ct * 16 + g * 4 + j;
      float v = cb[code * 16 + q];
      unsigned short h = f2bf(v);
      ch[j] = h;
      cl_[j] = f2bf(v - __uint_as_float((u32)h << 16));
    }
    uint2 hv = make_uint2((u32)ch[0] | ((u32)ch[1] << 16),
                          (u32)ch[2] | ((u32)ch[3] << 16));
    uint2 lv = make_uint2((u32)cl_[0] | ((u32)cl_[1] << 16),
                          (u32)cl_[2] | ((u32)cl_[3] << 16));
    *(uint2*)(chunk + 32768 + s * 1024 + l * 16 + par * 8) = hv;
    *(uint2*)(chunk + 40960 + s * 1024 + l * 16 + par * 8) = lv;
  }
  if (l < 16) {
    const int code = ct * 16 + l;
    *(float*)(chunk + 49152 + p * 64 + l * 4) = bm[code] * KS;
    *(float*)(chunk + 50176 + p * 64 + l * 4) = tp[code] * KS;
    float ss = 0.f;
#pragma unroll
    for (int d = 0; d < 16; d++) { float v = cb[code * 16 + d]; ss = fmaf(v, v, ss); }
    *(float*)(ws + WS_CC2B + code * 4) = ss;
  }
}

// 256 blocks x 512 thr (8 waves). Block owns 32 tokens = 2 token tiles; EVERY
// wave owns ONE subtile pair (s=wave) and computes BOTH token tiles from the
// same fragments (halves LDS reads vs per-tile wave groups).
// Precision: W,x,E,C all bf16 hi+lo (~2^-17); Cl*El term dropped.
// NaN-proofing: exponent clamped at 125, l2 floored (bug => finite diagnosis).
__global__ __launch_bounds__(512, 2) void flow_kernel(
    const float* __restrict__ x0, const char* __restrict__ ws,
    const float* __restrict__ cb, const int* __restrict__ nsp,
    float* __restrict__ out) {
  __shared__ __align__(16) char smem[106496];
  char* bufs = smem;                     // 2 x 51200 staging buffers
  float* xT = (float*)(smem + 102400);   // [32][16] base state
  float* xM = (float*)(smem + 104448);   // [32][16] midpoint state
  // scratch aliases buf0 (dead at point of use; next STAGE(0) is post-barrier):
  f4* redM = (f4*)smem;                  // [8][2][64] macc partials (16384 B)
  float* redL = (float*)(smem + 16384);  // [8][2][16] lsum per-token (1024 B)
  float* redV = (float*)(smem + 17408);  // [8][32] VQ min val
  int* redI = (int*)(smem + 18432);      // [8][32] VQ min idx
  const float* CC2 = (const float*)(ws + WS_CC2B);

  const int tid = threadIdx.x;
  const int lane = tid & 63, wave = tid >> 6;  // wave = pair id s = 0..7
  const int g = lane >> 4, q = lane & 15;
  const int tok0 = blockIdx.x * 32;

  if (tid < 128)
    *(float4*)(xT + tid * 4) = *(const float4*)(x0 + tok0 * 16 + tid * 4);
  __syncthreads();

  const int n_steps = *nsp;
  const float dt = 1.0f / (float)(n_steps - 1);

  auto STAGE = [&](int c) {  // one linear 51200-B chunk copy (dst off == src off)
    const char* src = ws + (size_t)c * CHB;
    char* db = bufs + (c & 1) * CHB;
#pragma unroll
    for (int r = 0; r < 6; r++)
      __builtin_amdgcn_global_load_lds(
          (const __attribute__((address_space(1))) u32*)(src + r * 8192 + tid * 16),
          (__attribute__((address_space(3))) u32*)(db + r * 8192 + wave * 1024),
          16, 0, 0);
    if (tid < 128)
      __builtin_amdgcn_global_load_lds(
          (const __attribute__((address_space(1))) u32*)(src + 49152 + tid * 16),
          (__attribute__((address_space(3))) u32*)(db + 49152 + wave * 1024),
          16, 0, 0);
  };

  for (int step = 0; step < n_steps - 1; step++) {
#pragma unroll 1
    for (int mh = 0; mh < 2; mh++) {
      const float tt = (float)step * dt + (mh ? 0.5f * dt : 0.0f);
      const float* xsrc = mh ? xM : xT;
      // B-frag of mfma1 per tile: col=tok=q, k=g*8+j; k<16->xh[d=k], else xl.
      union { u32 u[4]; s8v s; } Bx[2];
#pragma unroll
      for (int T = 0; T < 2; T++) {
        const float* xp = xsrc + (T * 16 + q) * 16 + (g & 1) * 8;
        float4 a = *(const float4*)(xp);
        float4 b = *(const float4*)(xp + 4);
        if (g < 2) {
          Bx[T].u[0] = pkbf(a.x, a.y); Bx[T].u[1] = pkbf(a.z, a.w);
          Bx[T].u[2] = pkbf(b.x, b.y); Bx[T].u[3] = pkbf(b.z, b.w);
        } else {
          Bx[T].u[0] = pkbf(a.x - bfhi(a.x), a.y - bfhi(a.y));
          Bx[T].u[1] = pkbf(a.z - bfhi(a.z), a.w - bfhi(a.w));
          Bx[T].u[2] = pkbf(b.x - bfhi(b.x), b.y - bfhi(b.y));
          Bx[T].u[3] = pkbf(b.z - bfhi(b.z), b.w - bfhi(b.w));
        }
      }
      f4 macc[2];
      float lsum[2];
#pragma unroll
      for (int T = 0; T < 2; T++) { macc[T] = (f4){0.f, 0.f, 0.f, 0.f}; lsum[T] = 0.f; }

      STAGE(0);
      __syncthreads();
#pragma unroll 1
      for (int c = 0; c < 32; c++) {
        if (c < 31) STAGE(c + 1);  // next chunk in flight under this compute
        const char* B = bufs + (c & 1) * CHB;
        const int s2 = wave * 2;
        s8v Ah0 = *(const s8v*)(B + s2 * 1024 + lane * 16);
        s8v Al0 = *(const s8v*)(B + 16384 + s2 * 1024 + lane * 16);
        s8v Ah1 = *(const s8v*)(B + (s2 + 1) * 1024 + lane * 16);
        s8v Al1 = *(const s8v*)(B + 16384 + (s2 + 1) * 1024 + lane * 16);
        s8v Ch = *(const s8v*)(B + 32768 + wave * 1024 + lane * 16);
        s8v Cl = *(const s8v*)(B + 40960 + wave * 1024 + lane * 16);
        float4 bb0 = *(const float4*)(B + 49152 + s2 * 64 + g * 16);
        float4 bt0 = *(const float4*)(B + 50176 + s2 * 64 + g * 16);
        float4 bb1 = *(const float4*)(B + 49152 + (s2 + 1) * 64 + g * 16);
        float4 bt1 = *(const float4*)(B + 50176 + (s2 + 1) * 64 + g * 16);
        float4 z0, z1;  // bias folded with tt (code = subtile*16 + g*4 + j)
        z0.x = fmaf(tt, bt0.x, bb0.x); z0.y = fmaf(tt, bt0.y, bb0.y);
        z0.z = fmaf(tt, bt0.z, bb0.z); z0.w = fmaf(tt, bt0.w, bb0.w);
        z1.x = fmaf(tt, bt1.x, bb1.x); z1.y = fmaf(tt, bt1.y, bb1.y);
        z1.z = fmaf(tt, bt1.z, bb1.z); z1.w = fmaf(tt, bt1.w, bb1.w);
#pragma unroll
        for (int T = 0; T < 2; T++) {
          f4 D0 = {0.f, 0.f, 0.f, 0.f};
          D0 = __builtin_amdgcn_mfma_f32_16x16x32_bf16(Ah0, Bx[T].s, D0, 0, 0, 0);
          D0 = __builtin_amdgcn_mfma_f32_16x16x32_bf16(Al0, Bx[T].s, D0, 0, 0, 0);
          f4 D1 = {0.f, 0.f, 0.f, 0.f};
          D1 = __builtin_amdgcn_mfma_f32_16x16x32_bf16(Ah1, Bx[T].s, D1, 0, 0, 0);
          D1 = __builtin_amdgcn_mfma_f32_16x16x32_bf16(Al1, Bx[T].s, D1, 0, 0, 0);
          float e0 = exp2f(fminf(D0[0] + z0.x, 125.f));
          float e1 = exp2f(fminf(D0[1] + z0.y, 125.f));
          float e2 = exp2f(fminf(D0[2] + z0.z, 125.f));
          float e3 = exp2f(fminf(D0[3] + z0.w, 125.f));
          float e4 = exp2f(fminf(D1[0] + z1.x, 125.f));
          float e5 = exp2f(fminf(D1[1] + z1.y, 125.f));
          float e6 = exp2f(fminf(D1[2] + z1.z, 125.f));
          float e7 = exp2f(fminf(D1[3] + z1.w, 125.f));
          lsum[T] += ((e0 + e1) + (e2 + e3)) + ((e4 + e5) + (e6 + e7));
          union { u32 u[4]; s8v s; } Eh, El;
          Eh.u[0] = pkbf(e0, e1); Eh.u[1] = pkbf(e2, e3);
          Eh.u[2] = pkbf(e4, e5); Eh.u[3] = pkbf(e6, e7);
          El.u[0] = pkbf(e0 - bfhi(e0), e1 - bfhi(e1));
          El.u[1] = pkbf(e2 - bfhi(e2), e3 - bfhi(e3));
          El.u[2] = pkbf(e4 - bfhi(e4), e5 - bfhi(e5));
          El.u[3] = pkbf(e6 - bfhi(e6), e7 - bfhi(e7));
          macc[T] = __builtin_amdgcn_mfma_f32_16x16x32_bf16(Ch, Eh.s, macc[T], 0, 0, 0);
          macc[T] = __builtin_amdgcn_mfma_f32_16x16x32_bf16(Ch, El.s, macc[T], 0, 0, 0);
          macc[T] = __builtin_amdgcn_mfma_f32_16x16x32_bf16(Cl, Eh.s, macc[T], 0, 0, 0);
        }
        if (c < 31) __syncthreads();  // stage drained + both buffers safe
      }
      // partials: macc per lane; lsum wave-reduced over g (lanes q,q+16,q+32,q+48)
#pragma unroll
      for (int T = 0; T < 2; T++) {
        lsum[T] += __shfl_xor(lsum[T], 16, 64);
        lsum[T] += __shfl_xor(lsum[T], 32, 64);
        redM[wave * 128 + T * 64 + lane] = macc[T];
      }
      if (lane < 16) {
        redL[wave * 32 + lane] = lsum[0];
        redL[wave * 32 + 16 + lane] = lsum[1];
      }
      __syncthreads();
      if (wave < 2) {  // wave T2 finalizes token tile T2
        const int T2 = wave;
        f4 m = redM[T2 * 64 + lane];
        float l2 = redL[T2 * 16 + q];
#pragma unroll
        for (int w = 1; w < 8; w++) {
          f4 o = redM[w * 128 + T2 * 64 + lane];
          m[0] += o[0]; m[1] += o[1]; m[2] += o[2]; m[3] += o[3];
          l2 += redL[w * 32 + T2 * 16 + q];
        }
        const float inv = 1.0f / fmaxf(l2, 1e-37f);
        const float inv1 = 1.0f / (1.0f - tt + 1e-10f);
        const float cf = (mh == 0) ? (0.5f * dt * inv1) : (dt * inv1);
        // lane owns (tok=q, d=g*4+j) of its tile: contiguous float4
        float4 xb = *(const float4*)(xT + (T2 * 16 + q) * 16 + g * 4);
        float4 xs = mh ? *(const float4*)(xM + (T2 * 16 + q) * 16 + g * 4) : xb;
        float4 xn;
        xn.x = fmaf(cf, m[0] * inv - xs.x, xb.x);
        xn.y = fmaf(cf, m[1] * inv - xs.y, xb.y);
        xn.z = fmaf(cf, m[2] * inv - xs.z, xb.z);
        xn.w = fmaf(cf, m[3] * inv - xs.w, xb.w);
        *(float4*)((mh ? xT : xM) + (T2 * 16 + q) * 16 + g * 4) = xn;
      }
      __syncthreads();
    }
  }

  // ---- outputs: x_final ----
  if (tid < 128)
    *(float4*)(out + tok0 * 16 + tid * 4) = *(const float4*)(xT + tid * 4);

  // ---- VQ argmin: d = ||c||^2 - 2 x.c; wave sweeps its 1024 codes for all
  // 32 tokens (4 at a time, fully unrolled: no runtime-indexed arrays). ----
  const int wbase = wave * 1024;
#pragma unroll 1
  for (int tg = 0; tg < 8; tg++) {
    float xr[4][16];
#pragma unroll
    for (int t = 0; t < 4; t++)
#pragma unroll
      for (int d4 = 0; d4 < 4; d4++)
        *(float4*)(&xr[t][d4 * 4]) = *(const float4*)(xT + (tg * 4 + t) * 16 + d4 * 4);
    float mv[4] = {3.402823466e38f, 3.402823466e38f, 3.402823466e38f, 3.402823466e38f};
    int mi[4] = {0, 0, 0, 0};
#pragma unroll 1
    for (int i = 0; i < 16; i++) {
      const int code = wbase + i * 64 + lane;
      float cr[16];
#pragma unroll
      for (int d4 = 0; d4 < 4; d4++)
        *(float4*)(&cr[d4 * 4]) = *(const float4*)(cb + code * 16 + d4 * 4);
      const float cc = CC2[code];
#pragma unroll
      for (int t = 0; t < 4; t++) {
        float dot = 0.f;
#pragma unroll
        for (int d = 0; d < 16; d++) dot = fmaf(xr[t][d], cr[d], dot);
        float dist = fmaf(-2.f, dot, cc);
        if (dist < mv[t]) { mv[t] = dist; mi[t] = code; }
      }
    }
#pragma unroll
    for (int t = 0; t < 4; t++) {
#pragma unroll
      for (int m = 1; m < 64; m <<= 1) {
        float ov = __shfl_xor(mv[t], m, 64);
        int oi = __shfl_xor(mi[t], m, 64);
        if (ov < mv[t] || (ov == mv[t] && oi < mi[t])) { mv[t] = ov; mi[t] = oi; }
      }
      if (lane == 0) {
        redV[wave * 32 + tg * 4 + t] = mv[t];
        redI[wave * 32 + tg * 4 + t] = mi[t];
      }
    }
  }
  __syncthreads();
  if (tid < 32) {
    float bv = redV[tid];
    int bi = redI[tid];
#pragma unroll
    for (int w = 1; w < 8; w++) {
      float ov = redV[w * 32 + tid];
      int oi = redI[w * 32 + tid];
      if (ov < bv || (ov == bv && oi < bi)) { bv = ov; bi = oi; }
    }
    out[NTOK * 16 + tok0 + tid] = (float)bi;
  }
}

extern "C" void kernel_launch(void* const* d_in, const int* in_sizes, int n_in,
                              void* d_out, int out_size, void* d_ws, size_t ws_size,
                              hipStream_t stream) {
  const float* x0 = (const float*)d_in[0];
  const float* cb = (const float*)d_in[1];
  const float* Wm = (const float*)d_in[2];
  const float* bm = (const float*)d_in[3];
  const float* tp = (const float*)d_in[4];
  const int* ns = (const int*)d_in[5];
  char* ws = (char*)d_ws;  // needs 1671168 B
  float* out = (float*)d_out;

  prep_kernel<<<512, 64, 0, stream>>>(cb, Wm, bm, tp, ws);
  flow_kernel<<<256, 512, 0, stream>>>(x0, ws, cb, ns, out);
}

// Round 4
// 660.179 us; speedup vs baseline: 2.4542x; 1.2623x over previous
//
#include <hip/hip_runtime.h>

#define KS 1.8033688011112042f  // log2(e)/0.8
#define NTOK 8192
#define VV 8192
#define CHB 51200
#define WS_CC2B 1638400

typedef float f4 __attribute__((ext_vector_type(4)));
typedef short s8v __attribute__((ext_vector_type(8)));
typedef unsigned int u32;

// RNE float->bf16, bit-ops (prep only — cold)
static __device__ __forceinline__ unsigned short f2bf(float f) {
  u32 u = __float_as_uint(f);
  return (unsigned short)((u + 0x7fffu + ((u >> 16) & 1u)) >> 16);
}
// HW packed conversion: D.lo16 = bf16(a), D.hi16 = bf16(b)  (T12 recipe form)
static __device__ __forceinline__ u32 cvtpk(float a, float b) {
  u32 r;
  asm("v_cvt_pk_bf16_f32 %0, %1, %2" : "=v"(r) : "v"(a), "v"(b));
  return r;
}
static __device__ __forceinline__ float lof(u32 h) {  // low bf16 as f32
  return __uint_as_float(h << 16);
}
static __device__ __forceinline__ float hif(u32 h) {  // high bf16 as f32
  return __uint_as_float(h & 0xffff0000u);
}

// ws layout: 32 chunks (256 codes), chunk-major, one linear 51200-B copy each:
//   [0     ,16384) FragWh : 16 subtiles x 64 lanes x 8 bf16 (A of mfma1, W_hi*KS)
//   [16384 ,32768) FragWl
//   [32768 ,40960) FragCh : 8 PAIRS x 64 lanes x 8 bf16 (A of mfma2, K=32 pairing)
//   [40960 ,49152) FragCl
//   [49152 ,50176) BB fp32[256] (b*KS)   [50176,51200) BT fp32[256] (tp*KS)
// then CC2 fp32[8192]. Total 1671168 B.
// ALL mfma are 16x16x32_bf16 (layout validated by the refcheck'd GEMM ladder).
// mfma1 (logits^T): M=code16, N=tok16, K=32 ([xh;xl]); A repeats W over d=k&15.
// mfma2 (mu^T): M=d16, N=tok16, K=32 over a subtile PAIR (p0=2s, p1=2s+1):
//   k=g*8+j -> code = (j<4 ? p0 : p1)*16 + g*4 + (j&3); B elem j = E[code][tok]
//   which is exactly the e-vector a lane holds from mfma1's D of p0,p1.
__global__ __launch_bounds__(64) void prep_kernel(
    const float* __restrict__ cb, const float* __restrict__ Wm,
    const float* __restrict__ bm, const float* __restrict__ tp,
    char* __restrict__ ws) {
  const int ct = blockIdx.x;  // subtile 0..511 (16 codes)
  const int l = threadIdx.x;
  const int g = l >> 4, q = l & 15;
  const int c = ct >> 4, p = ct & 15;
  const int s = p >> 1, par = p & 1;
  char* chunk = ws + (size_t)c * CHB;
  {  // W fragment (A of mfma1): row=code=ct*16+q, k=g*8+j, d=k&15
    const int code = ct * 16 + q;
    unsigned short wh[8], wl[8];
#pragma unroll
    for (int j = 0; j < 8; j++) {
      int d = (g * 8 + j) & 15;
      float v = Wm[d * VV + code] * KS;
      unsigned short h = f2bf(v);
      wh[j] = h;
      wl[j] = f2bf(v - __uint_as_float((u32)h << 16));
    }
    uint4 hv, lv;
    hv.x = (u32)wh[0] | ((u32)wh[1] << 16); hv.y = (u32)wh[2] | ((u32)wh[3] << 16);
    hv.z = (u32)wh[4] | ((u32)wh[5] << 16); hv.w = (u32)wh[6] | ((u32)wh[7] << 16);
    lv.x = (u32)wl[0] | ((u32)wl[1] << 16); lv.y = (u32)wl[2] | ((u32)wl[3] << 16);
    lv.z = (u32)wl[4] | ((u32)wl[5] << 16); lv.w = (u32)wl[6] | ((u32)wl[7] << 16);
    *(uint4*)(chunk + p * 1024 + l * 16) = hv;
    *(uint4*)(chunk + 16384 + p * 1024 + l * 16) = lv;
  }
  {  // C pair-fragment (A of mfma2): block fills elems par*4+{0..3} of pair s
    unsigned short ch[4], cl_[4];
#pragma unroll
    for (int j = 0; j < 4; j++) {
      int code = ct * 16 + g * 4 + j;
      float v = cb[code * 16 + q];
      unsigned short h = f2bf(v);
      ch[j] = h;
      cl_[j] = f2bf(v - __uint_as_float((u32)h << 16));
    }
    uint2 hv = make_uint2((u32)ch[0] | ((u32)ch[1] << 16),
                          (u32)ch[2] | ((u32)ch[3] << 16));
    uint2 lv = make_uint2((u32)cl_[0] | ((u32)cl_[1] << 16),
                          (u32)cl_[2] | ((u32)cl_[3] << 16));
    *(uint2*)(chunk + 32768 + s * 1024 + l * 16 + par * 8) = hv;
    *(uint2*)(chunk + 40960 + s * 1024 + l * 16 + par * 8) = lv;
  }
  if (l < 16) {
    const int code = ct * 16 + l;
    *(float*)(chunk + 49152 + p * 64 + l * 4) = bm[code] * KS;
    *(float*)(chunk + 50176 + p * 64 + l * 4) = tp[code] * KS;
    float ss = 0.f;
#pragma unroll
    for (int d = 0; d < 16; d++) { float v = cb[code * 16 + d]; ss = fmaf(v, v, ss); }
    *(float*)(ws + WS_CC2B + code * 4) = ss;
  }
}

// 256 blocks x 1024 thr (16 waves = 4 waves/SIMD, 1 block/CU). Block owns 32
// tokens = 2 token tiles. wave = (pair s = wave&7, tile T = wave>>3): each wave
// computes ONE tile from pair s (fragments read by both T-siblings; LDS port
// has headroom). All bf16 packing via HW v_cvt_pk_bf16_f32; El/xl unpacked
// from the packed words -> split self-consistent regardless of round mode.
// NaN-proofing: exponent clamp 125, l2 floored.
__global__ __launch_bounds__(1024, 4) void flow_kernel(
    const float* __restrict__ x0, const char* __restrict__ ws,
    const float* __restrict__ cb, const int* __restrict__ nsp,
    float* __restrict__ out) {
  __shared__ __align__(16) char smem[106496];
  char* bufs = smem;                     // 2 x 51200 staging buffers
  float* xT = (float*)(smem + 102400);   // [32][16] base state
  float* xM = (float*)(smem + 104448);   // [32][16] midpoint state
  // scratch aliases buf0 (dead at point of use; next STAGE(0) is post-barrier):
  f4* redM = (f4*)smem;                  // [16][64] macc partials (16384 B)
  float* redL = (float*)(smem + 16384);  // [16][16] lsum per-token (1024 B)
  float* redV = (float*)(smem + 17408);  // [16][32] VQ min val
  int* redI = (int*)(smem + 19456);      // [16][32] VQ min idx
  const float* CC2 = (const float*)(ws + WS_CC2B);

  const int tid = threadIdx.x;
  const int lane = tid & 63, wave = tid >> 6;  // 16 waves
  const int T = wave >> 3, s = wave & 7;
  const int g = lane >> 4, q = lane & 15;
  const int tok0 = blockIdx.x * 32;

  if (tid < 128)
    *(float4*)(xT + tid * 4) = *(const float4*)(x0 + tok0 * 16 + tid * 4);
  __syncthreads();

  const int n_steps = *nsp;
  const float dt = 1.0f / (float)(n_steps - 1);

  auto STAGE = [&](int c) {  // one linear 51200-B chunk copy (dst off == src off)
    const char* src = ws + (size_t)c * CHB;
    char* db = bufs + (c & 1) * CHB;
#pragma unroll
    for (int r = 0; r < 3; r++)
      __builtin_amdgcn_global_load_lds(
          (const __attribute__((address_space(1))) u32*)(src + r * 16384 + tid * 16),
          (__attribute__((address_space(3))) u32*)(db + r * 16384 + wave * 1024),
          16, 0, 0);
    if (tid < 128)
      __builtin_amdgcn_global_load_lds(
          (const __attribute__((address_space(1))) u32*)(src + 49152 + tid * 16),
          (__attribute__((address_space(3))) u32*)(db + 49152 + wave * 1024),
          16, 0, 0);
  };

  for (int step = 0; step < n_steps - 1; step++) {
#pragma unroll 1
    for (int mh = 0; mh < 2; mh++) {
      const float tt = (float)step * dt + (mh ? 0.5f * dt : 0.0f);
      const float* xsrc = mh ? xM : xT;
      // B-frag of mfma1 for this wave's tile: col=tok=q, k=g*8+j;
      // k<16 -> xh[d=k], k>=16 -> xl[d=k-16]. Group g covers d=(g&1)*8..+7.
      union { u32 u[4]; s8v s; } Bx;
      {
        const float* xp = xsrc + (T * 16 + q) * 16 + (g & 1) * 8;
        float4 a = *(const float4*)(xp);
        float4 b = *(const float4*)(xp + 4);
        u32 h0 = cvtpk(a.x, a.y), h1 = cvtpk(a.z, a.w);
        u32 h2 = cvtpk(b.x, b.y), h3 = cvtpk(b.z, b.w);
        if (g < 2) {
          Bx.u[0] = h0; Bx.u[1] = h1; Bx.u[2] = h2; Bx.u[3] = h3;
        } else {
          Bx.u[0] = cvtpk(a.x - lof(h0), a.y - hif(h0));
          Bx.u[1] = cvtpk(a.z - lof(h1), a.w - hif(h1));
          Bx.u[2] = cvtpk(b.x - lof(h2), b.y - hif(h2));
          Bx.u[3] = cvtpk(b.z - lof(h3), b.w - hif(h3));
        }
      }
      f4 macc = {0.f, 0.f, 0.f, 0.f};
      float lsum = 0.f;

      STAGE(0);
      __syncthreads();
#pragma unroll 1
      for (int c = 0; c < 32; c++) {
        if (c < 31) STAGE(c + 1);  // next chunk in flight under this compute
        const char* B = bufs + (c & 1) * CHB;
        const int s2 = s * 2;
        s8v Ah0 = *(const s8v*)(B + s2 * 1024 + lane * 16);
        s8v Al0 = *(const s8v*)(B + 16384 + s2 * 1024 + lane * 16);
        s8v Ah1 = *(const s8v*)(B + (s2 + 1) * 1024 + lane * 16);
        s8v Al1 = *(const s8v*)(B + 16384 + (s2 + 1) * 1024 + lane * 16);
        s8v Ch = *(const s8v*)(B + 32768 + s * 1024 + lane * 16);
        s8v Cl = *(const s8v*)(B + 40960 + s * 1024 + lane * 16);
        float4 bb0 = *(const float4*)(B + 49152 + s2 * 64 + g * 16);
        float4 bt0 = *(const float4*)(B + 50176 + s2 * 64 + g * 16);
        float4 bb1 = *(const float4*)(B + 49152 + (s2 + 1) * 64 + g * 16);
        float4 bt1 = *(const float4*)(B + 50176 + (s2 + 1) * 64 + g * 16);
        float4 z0, z1;  // bias folded with tt
        z0.x = fmaf(tt, bt0.x, bb0.x); z0.y = fmaf(tt, bt0.y, bb0.y);
        z0.z = fmaf(tt, bt0.z, bb0.z); z0.w = fmaf(tt, bt0.w, bb0.w);
        z1.x = fmaf(tt, bt1.x, bb1.x); z1.y = fmaf(tt, bt1.y, bb1.y);
        z1.z = fmaf(tt, bt1.z, bb1.z); z1.w = fmaf(tt, bt1.w, bb1.w);
        f4 D0 = {0.f, 0.f, 0.f, 0.f};
        D0 = __builtin_amdgcn_mfma_f32_16x16x32_bf16(Ah0, Bx.s, D0, 0, 0, 0);
        D0 = __builtin_amdgcn_mfma_f32_16x16x32_bf16(Al0, Bx.s, D0, 0, 0, 0);
        f4 D1 = {0.f, 0.f, 0.f, 0.f};
        D1 = __builtin_amdgcn_mfma_f32_16x16x32_bf16(Ah1, Bx.s, D1, 0, 0, 0);
        D1 = __builtin_amdgcn_mfma_f32_16x16x32_bf16(Al1, Bx.s, D1, 0, 0, 0);
        float e0 = exp2f(fminf(D0[0] + z0.x, 125.f));
        float e1 = exp2f(fminf(D0[1] + z0.y, 125.f));
        float e2 = exp2f(fminf(D0[2] + z0.z, 125.f));
        float e3 = exp2f(fminf(D0[3] + z0.w, 125.f));
        float e4 = exp2f(fminf(D1[0] + z1.x, 125.f));
        float e5 = exp2f(fminf(D1[1] + z1.y, 125.f));
        float e6 = exp2f(fminf(D1[2] + z1.z, 125.f));
        float e7 = exp2f(fminf(D1[3] + z1.w, 125.f));
        lsum += ((e0 + e1) + (e2 + e3)) + ((e4 + e5) + (e6 + e7));
        union { u32 u[4]; s8v s; } Eh, El;
        Eh.u[0] = cvtpk(e0, e1); Eh.u[1] = cvtpk(e2, e3);
        Eh.u[2] = cvtpk(e4, e5); Eh.u[3] = cvtpk(e6, e7);
        // lows unpacked from the packed his -> split exact by construction
        El.u[0] = cvtpk(e0 - lof(Eh.u[0]), e1 - hif(Eh.u[0]));
        El.u[1] = cvtpk(e2 - lof(Eh.u[1]), e3 - hif(Eh.u[1]));
        El.u[2] = cvtpk(e4 - lof(Eh.u[2]), e5 - hif(Eh.u[2]));
        El.u[3] = cvtpk(e6 - lof(Eh.u[3]), e7 - hif(Eh.u[3]));
        macc = __builtin_amdgcn_mfma_f32_16x16x32_bf16(Ch, Eh.s, macc, 0, 0, 0);
        macc = __builtin_amdgcn_mfma_f32_16x16x32_bf16(Ch, El.s, macc, 0, 0, 0);
        macc = __builtin_amdgcn_mfma_f32_16x16x32_bf16(Cl, Eh.s, macc, 0, 0, 0);
        if (c < 31) __syncthreads();  // stage drained + both buffers safe
      }
      // partials: lsum reduced over g (lanes q,q+16,q+32,q+48), macc per lane
      lsum += __shfl_xor(lsum, 16, 64);
      lsum += __shfl_xor(lsum, 32, 64);
      redM[wave * 64 + lane] = macc;
      if (lane < 16) redL[wave * 16 + lane] = lsum;
      __syncthreads();
      if ((wave & 7) == 0) {  // waves 0 (T0) and 8 (T1) finalize their tile
        const int T2 = wave >> 3;
        f4 m = redM[(T2 * 8) * 64 + lane];
        float l2 = redL[(T2 * 8) * 16 + q];
#pragma unroll
        for (int w = 1; w < 8; w++) {
          f4 o = redM[(T2 * 8 + w) * 64 + lane];
          m[0] += o[0]; m[1] += o[1]; m[2] += o[2]; m[3] += o[3];
          l2 += redL[(T2 * 8 + w) * 16 + q];
        }
        const float inv = 1.0f / fmaxf(l2, 1e-37f);
        const float inv1 = 1.0f / (1.0f - tt + 1e-10f);
        const float cf = (mh == 0) ? (0.5f * dt * inv1) : (dt * inv1);
        // lane owns (tok=q, d=g*4+j) of its tile: contiguous float4
        float4 xb = *(const float4*)(xT + (T2 * 16 + q) * 16 + g * 4);
        float4 xs = mh ? *(const float4*)(xM + (T2 * 16 + q) * 16 + g * 4) : xb;
        float4 xn;
        xn.x = fmaf(cf, m[0] * inv - xs.x, xb.x);
        xn.y = fmaf(cf, m[1] * inv - xs.y, xb.y);
        xn.z = fmaf(cf, m[2] * inv - xs.z, xb.z);
        xn.w = fmaf(cf, m[3] * inv - xs.w, xb.w);
        *(float4*)((mh ? xT : xM) + (T2 * 16 + q) * 16 + g * 4) = xn;
      }
      __syncthreads();
    }
  }

  // ---- outputs: x_final ----
  if (tid < 128)
    *(float4*)(out + tok0 * 16 + tid * 4) = *(const float4*)(xT + tid * 4);

  // ---- VQ argmin: d = ||c||^2 - 2 x.c; wave sweeps its 512 codes for all
  // 32 tokens (4 at a time, fully unrolled: no runtime-indexed arrays). ----
  const int wbase = wave * 512;
#pragma unroll 1
  for (int tg = 0; tg < 8; tg++) {
    float xr[4][16];
#pragma unroll
    for (int t = 0; t < 4; t++)
#pragma unroll
      for (int d4 = 0; d4 < 4; d4++)
        *(float4*)(&xr[t][d4 * 4]) = *(const float4*)(xT + (tg * 4 + t) * 16 + d4 * 4);
    float mv[4] = {3.402823466e38f, 3.402823466e38f, 3.402823466e38f, 3.402823466e38f};
    int mi[4] = {0, 0, 0, 0};
#pragma unroll 1
    for (int i = 0; i < 8; i++) {
      const int code = wbase + i * 64 + lane;
      float cr[16];
#pragma unroll
      for (int d4 = 0; d4 < 4; d4++)
        *(float4*)(&cr[d4 * 4]) = *(const float4*)(cb + code * 16 + d4 * 4);
      const float cc = CC2[code];
#pragma unroll
      for (int t = 0; t < 4; t++) {
        float dot = 0.f;
#pragma unroll
        for (int d = 0; d < 16; d++) dot = fmaf(xr[t][d], cr[d], dot);
        float dist = fmaf(-2.f, dot, cc);
        if (dist < mv[t]) { mv[t] = dist; mi[t] = code; }
      }
    }
#pragma unroll
    for (int t = 0; t < 4; t++) {
#pragma unroll
      for (int m = 1; m < 64; m <<= 1) {
        float ov = __shfl_xor(mv[t], m, 64);
        int oi = __shfl_xor(mi[t], m, 64);
        if (ov < mv[t] || (ov == mv[t] && oi < mi[t])) { mv[t] = ov; mi[t] = oi; }
      }
      if (lane == 0) {
        redV[wave * 32 + tg * 4 + t] = mv[t];
        redI[wave * 32 + tg * 4 + t] = mi[t];
      }
    }
  }
  __syncthreads();
  if (tid < 32) {
    float bv = redV[tid];
    int bi = redI[tid];
#pragma unroll
    for (int w = 1; w < 16; w++) {
      float ov = redV[w * 32 + tid];
      int oi = redI[w * 32 + tid];
      if (ov < bv || (ov == bv && oi < bi)) { bv = ov; bi = oi; }
    }
    out[NTOK * 16 + tok0 + tid] = (float)bi;
  }
}

extern "C" void kernel_launch(void* const* d_in, const int* in_sizes, int n_in,
                              void* d_out, int out_size, void* d_ws, size_t ws_size,
                              hipStream_t stream) {
  const float* x0 = (const float*)d_in[0];
  const float* cb = (const float*)d_in[1];
  const float* Wm = (const float*)d_in[2];
  const float* bm = (const float*)d_in[3];
  const float* tp = (const float*)d_in[4];
  const int* ns = (const int*)d_in[5];
  char* ws = (char*)d_ws;  // needs 1671168 B
  float* out = (float*)d_out;

  prep_kernel<<<512, 64, 0, stream>>>(cb, Wm, bm, tp, ws);
  flow_kernel<<<256, 1024, 0, stream>>>(x0, ws, cb, ns, out);
}